// Round 5
// baseline (14.876 us; speedup 1.0000x reference)
//
#include <hip/hip_runtime.h>

// RTL (random tiny lattice) layer:
//   x: (2048, 128) f32, kernel: (81, 1024) f32, indices: (1024, 4) i32
//   out[b,l] = 16-point multilinear interp of kernel[:, l] at x[b, idx[l,:]]
//
// Vertex v = 27v0+9v1+3v2+v3. The 16 needed vertices form 4 clusters
// {u,u+1,u+3,u+4}, u = 9*(3*i0+i1+3a+b) + 3*i2+i3, (a,b) in {0,1}^2.
// LDS holds every possible cluster as a contiguous float4:
//   Kq[q][l], q = 4*m + (2*i2+i3), m = 0..8 -> 36 quads, 36 KB.
// Inner loop per output: exactly 4x ds_read_b128 (imm offsets, conflict-free:
// bank = 4*lane mod 32, independent of data-dependent q). x-gathers go to the
// VMEM pipe (same-row L1-friendly). Grid = 256 blocks x 1024 threads = exactly
// one block per CU: all staging/idx latency is paid once, zero block rounds.

#define NFEAT   128
#define NLAT    1024
#define BATCH   2048
#define LT      64     // lattices per block (= wave width)
#define BT      128    // batch rows per block
#define THREADS 1024
#define NQUAD   36

__global__ __launch_bounds__(THREADS, 4)
void rtl_kernel(const float* __restrict__ x,
                const float* __restrict__ kern,
                const int*   __restrict__ indices,
                float*       __restrict__ out) {
    __shared__ float4 Kq[NQUAD * LT];   // 36 KB

    const int tid   = threadIdx.x;
    const int ltile = blockIdx.x & 15;   // 16 lattice tiles
    const int btile = blockIdx.x >> 4;   // 16 batch tiles
    const int l0    = ltile * LT;
    const int b0    = btile * BT;

    const int lane = tid & 63;
    const int wid  = tid >> 6;           // wave id 0..15, owns 8 batch rows
    const int brow = b0 + wid * 8;

    // ---- issue x-gathers up front: 32 independent loads into registers ----
    const int4 idx = *(const int4*)(indices + (l0 + lane) * 4);
    float xv[8][4];
#pragma unroll
    for (int k = 0; k < 8; ++k) {
        const float* xr = x + (brow + k) * NFEAT;
        xv[k][0] = xr[idx.x];
        xv[k][1] = xr[idx.y];
        xv[k][2] = xr[idx.z];
        xv[k][3] = xr[idx.w];
    }

    // ---- stage quad-replicated kernel slice: 2304 float4 slots ----
    for (int i = tid; i < NQUAD * LT; i += THREADS) {
        const int q  = i >> 6;
        const int l  = i & (LT - 1);
        const int m  = q >> 2;
        const int jj = q & 3;            // 2*i2 + i3
        const int u  = 9 * m + 3 * (jj >> 1) + (jj & 1);
        const float* kp = kern + u * NLAT + l0 + l;
        Kq[i] = make_float4(kp[0], kp[NLAT], kp[3 * NLAT], kp[4 * NLAT]);
    }

    __syncthreads();

    const float4* col = Kq + lane;       // element q at col[q*64]
    float* orow = out + brow * NLAT + l0 + lane;

#pragma unroll
    for (int k = 0; k < 8; ++k) {
        float x0 = fminf(fmaxf(xv[k][0], 0.0f), 2.0f);
        float x1 = fminf(fmaxf(xv[k][1], 0.0f), 2.0f);
        float x2 = fminf(fmaxf(xv[k][2], 0.0f), 2.0f);
        float x3 = fminf(fmaxf(xv[k][3], 0.0f), 2.0f);

        const int  i0 = (x0 >= 1.0f);  const float t0 = x0 - (float)i0;
        const int  i1 = (x1 >= 1.0f);  const float t1 = x1 - (float)i1;
        const int  i2 = (x2 >= 1.0f);  const float t2 = x2 - (float)i2;
        const int  i3 = (x3 >= 1.0f);  const float t3 = x3 - (float)i3;

        const int q00 = 12 * i0 + 4 * i1 + 2 * i2 + i3;
        const float4* cq = col + q00 * LT;

        // clusters (a,b): +0, +4 (b=1), +12 (a=1), +16 (a=1,b=1) quads
        const float4 fA = cq[0];
        const float4 fB = cq[4 * LT];
        const float4 fC = cq[12 * LT];
        const float4 fD = cq[16 * LT];

        const float eA0 = fmaf(t3, fA.y - fA.x, fA.x);
        const float eA1 = fmaf(t3, fA.w - fA.z, fA.z);
        const float cA  = fmaf(t2, eA1 - eA0, eA0);
        const float eB0 = fmaf(t3, fB.y - fB.x, fB.x);
        const float eB1 = fmaf(t3, fB.w - fB.z, fB.z);
        const float cB  = fmaf(t2, eB1 - eB0, eB0);
        const float eC0 = fmaf(t3, fC.y - fC.x, fC.x);
        const float eC1 = fmaf(t3, fC.w - fC.z, fC.z);
        const float cC  = fmaf(t2, eC1 - eC0, eC0);
        const float eD0 = fmaf(t3, fD.y - fD.x, fD.x);
        const float eD1 = fmaf(t3, fD.w - fD.z, fD.z);
        const float cD  = fmaf(t2, eD1 - eD0, eD0);

        const float n0  = fmaf(t1, cB - cA, cA);
        const float n1  = fmaf(t1, cD - cC, cC);
        const float res = fmaf(t0, n1 - n0, n0);

        orow[k * NLAT] = res;
    }
}

extern "C" void kernel_launch(void* const* d_in, const int* in_sizes, int n_in,
                              void* d_out, int out_size, void* d_ws, size_t ws_size,
                              hipStream_t stream) {
    const float* x       = (const float*)d_in[0];
    const float* kern    = (const float*)d_in[1];
    const int*   indices = (const int*)d_in[2];
    float*       out     = (float*)d_out;

    const int grid = (NLAT / LT) * (BATCH / BT);  // 16 * 16 = 256 = 1 per CU
    rtl_kernel<<<grid, THREADS, 0, stream>>>(x, kern, indices, out);
}

// Round 6
// 11.370 us; speedup vs baseline: 1.3083x; 1.3083x over previous
//
#include <hip/hip_runtime.h>

// RTL (random tiny lattice) layer:
//   x: (2048, 128) f32, kernel: (81, 1024) f32, indices: (1024, 4) i32
//   out[b,l] = 16-point multilinear interp of kernel[:, l] at x[b, idx[l,:]]
//
// Vertex v = 27v0+9v1+3v2+v3. The 16 needed vertices form 4 clusters
// {u,u+1,u+3,u+4}, u = 9*(3*i0+i1+3a+b) + 3*i2+i3, (a,b) in {0,1}^2.
// LDS: every possible cluster as a contiguous float4:
//   Kq[q][l], q = 4*m + (2*i2+i3), m = 0..8  -> 36 quads, 36 KB
// plus the x tile (32 KB). Inner loop per output: exactly 4x ds_read_b128
// (imm offsets, conflict-free: bank = 4*lane mod 32, independent of the
// data-dependent q) + 15 FMA. All x-gathers + cell/frac preprocessing are
// hoisted before the loop (32 independent ds_read_b32, pipelined).

#define NFEAT   128
#define NLAT    1024
#define BATCH   2048
#define LT      64     // lattices per block (= wave width)
#define BT      64     // batch rows per block
#define THREADS 512
#define NQUAD   36

__global__ __launch_bounds__(THREADS, 4)   // 2 blocks/CU (LDS-capped), 16 waves/CU
void rtl_kernel(const float* __restrict__ x,
                const float* __restrict__ kern,
                const int*   __restrict__ indices,
                float*       __restrict__ out) {
    __shared__ float4 Kq[NQUAD * LT];   // 36 KB
    __shared__ float  Xl[BT * NFEAT];   // 32 KB

    const int tid   = threadIdx.x;
    const int ltile = blockIdx.x & 15;   // 16 lattice tiles
    const int btile = blockIdx.x >> 4;   // 32 batch tiles
    const int l0    = ltile * LT;
    const int b0    = btile * BT;

    // ---- stage x tile: 64 rows x 128 f32 = 2048 float4, fully coalesced ----
    {
        float4* dst = (float4*)Xl;
        const float4* src = (const float4*)(x + b0 * NFEAT);
        #pragma unroll
        for (int i = tid; i < (BT * NFEAT) / 4; i += THREADS) dst[i] = src[i];
    }
    // ---- stage quad-replicated kernel slice (4.5 float4 per thread) ----
    for (int i = tid; i < NQUAD * LT; i += THREADS) {
        const int q  = i >> 6;
        const int l  = i & (LT - 1);
        const int m  = q >> 2;
        const int jj = q & 3;            // 2*i2 + i3
        const int u  = 9 * m + 3 * (jj >> 1) + (jj & 1);
        const float* kp = kern + u * NLAT + l0 + l;
        Kq[i] = make_float4(kp[0], kp[NLAT], kp[3 * NLAT], kp[4 * NLAT]);
    }

    const int lane = tid & 63;
    const int wid  = tid >> 6;           // wave id 0..7, owns 8 batch rows
    const int4 idx = *(const int4*)(indices + (l0 + lane) * 4);

    __syncthreads();

    // ---- hoist: all 32 x-gathers + preprocessing into registers ----
    float t0r[8], t1r[8], t2r[8], t3r[8];
    int   qr[8];
#pragma unroll
    for (int k = 0; k < 8; ++k) {
        const float* xr = Xl + (wid * 8 + k) * NFEAT;
        const float x0 = fminf(fmaxf(xr[idx.x], 0.0f), 2.0f);
        const float x1 = fminf(fmaxf(xr[idx.y], 0.0f), 2.0f);
        const float x2 = fminf(fmaxf(xr[idx.z], 0.0f), 2.0f);
        const float x3 = fminf(fmaxf(xr[idx.w], 0.0f), 2.0f);
        const int i0 = (x0 >= 1.0f);
        const int i1 = (x1 >= 1.0f);
        const int i2 = (x2 >= 1.0f);
        const int i3 = (x3 >= 1.0f);
        t0r[k] = x0 - (float)i0;
        t1r[k] = x1 - (float)i1;
        t2r[k] = x2 - (float)i2;
        t3r[k] = x3 - (float)i3;
        qr[k]  = 12 * i0 + 4 * i1 + 2 * i2 + i3;
    }

    const float4* col = Kq + lane;       // element q at col[q*64]
    float* orow = out + (b0 + wid * 8) * NLAT + l0 + lane;

    // ---- pure loop: 4x ds_read_b128 + lerp tree + coalesced store ----
#pragma unroll
    for (int k = 0; k < 8; ++k) {
        const float t0 = t0r[k], t1 = t1r[k], t2 = t2r[k], t3 = t3r[k];
        const float4* cq = col + qr[k] * LT;

        const float4 fA = cq[0];
        const float4 fB = cq[4 * LT];    // b=1
        const float4 fC = cq[12 * LT];   // a=1
        const float4 fD = cq[16 * LT];   // a=1,b=1

        const float eA0 = fmaf(t3, fA.y - fA.x, fA.x);
        const float eA1 = fmaf(t3, fA.w - fA.z, fA.z);
        const float cA  = fmaf(t2, eA1 - eA0, eA0);
        const float eB0 = fmaf(t3, fB.y - fB.x, fB.x);
        const float eB1 = fmaf(t3, fB.w - fB.z, fB.z);
        const float cB  = fmaf(t2, eB1 - eB0, eB0);
        const float eC0 = fmaf(t3, fC.y - fC.x, fC.x);
        const float eC1 = fmaf(t3, fC.w - fC.z, fC.z);
        const float cC  = fmaf(t2, eC1 - eC0, eC0);
        const float eD0 = fmaf(t3, fD.y - fD.x, fD.x);
        const float eD1 = fmaf(t3, fD.w - fD.z, fD.z);
        const float cD  = fmaf(t2, eD1 - eD0, eD0);

        const float n0  = fmaf(t1, cB - cA, cA);
        const float n1  = fmaf(t1, cD - cC, cC);
        const float res = fmaf(t0, n1 - n0, n0);

        orow[k * NLAT] = res;
    }
}

extern "C" void kernel_launch(void* const* d_in, const int* in_sizes, int n_in,
                              void* d_out, int out_size, void* d_ws, size_t ws_size,
                              hipStream_t stream) {
    const float* x       = (const float*)d_in[0];
    const float* kern    = (const float*)d_in[1];
    const int*   indices = (const int*)d_in[2];
    float*       out     = (float*)d_out;

    const int grid = (NLAT / LT) * (BATCH / BT);  // 16 * 32 = 512 = 2 per CU
    rtl_kernel<<<grid, THREADS, 0, stream>>>(x, kern, indices, out);
}